// Round 10
// baseline (860.987 us; speedup 1.0000x reference)
//
#include <hip/hip_runtime.h>
#include <stdint.h>

#define NBLOCKS 256
#define WPB 8                          // waves per block (512 threads), 1 block/CU
#define SLOTS (NBLOCKS * WPB)          // 2048 independent wave slots
#define TILE_BYTES 16384               // 32 rows x 256 bf16 cols x 2B = 16 KB (!)
#define SMEM_BYTES (WPB * TILE_BYTES)  // 128 KB: single buffer per wave

typedef __attribute__((ext_vector_type(8))) short bfrag_t;
typedef __attribute__((ext_vector_type(4))) float f32x4;
typedef __attribute__((ext_vector_type(2))) unsigned int u32x2;

static __device__ __forceinline__ unsigned short f2bf(float f) {
  unsigned int u = __float_as_uint(f);
  u += 0x7fffu + ((u >> 16) & 1u);   // RNE
  return (unsigned short)(u >> 16);
}

static __device__ __forceinline__ float tanh_fast(float s) {
  // tanh(s) = 1 - 2/(1+e^{2s}); saturates at +-1, no clamp needed
  float e = __builtin_exp2f(s * 2.8853900817779268f);
  float r = __builtin_amdgcn_rcpf(1.f + e);
  return __builtin_fmaf(-2.f, r, 1.f);
}

// readlane for floats: BIT-cast (int builtin; float would value-truncate — r4 bug)
static __device__ __forceinline__ float readlane_f(float v, int l) {
  return __uint_as_float(__builtin_amdgcn_readlane(__float_as_uint(v), l));
}

static __device__ __forceinline__ bfrag_t pack8(f32x4 a, f32x4 b) {
  union { bfrag_t v; unsigned int u[4]; } r;
  asm("v_cvt_pk_bf16_f32 %0, %1, %2" : "=v"(r.u[0]) : "v"(a[0]), "v"(a[1]));
  asm("v_cvt_pk_bf16_f32 %0, %1, %2" : "=v"(r.u[1]) : "v"(a[2]), "v"(a[3]));
  asm("v_cvt_pk_bf16_f32 %0, %1, %2" : "=v"(r.u[2]) : "v"(b[0]), "v"(b[1]));
  asm("v_cvt_pk_bf16_f32 %0, %1, %2" : "=v"(r.u[3]) : "v"(b[2]), "v"(b[3]));
  return r.v;
}

// Pre-swizzle W1 (f32 [256][256], k-major) into MFMA B-fragment order, bf16.
// W1f[((cc*8+kk)*64 + lane)*8 + j] = bf16(W1[kk*32 + 8*(lane>>4) + j][cc*16 + (lane&15)])
__global__ void prep_w1_kernel(const float* __restrict__ W1, unsigned short* __restrict__ W1f) {
  const int bx = blockIdx.x;   // cc*8 + kk, 0..127
  const int l = threadIdx.x;   // 0..63
  const int cc = bx >> 3, kk = bx & 7;
  const int h = cc * 16 + (l & 15);
  const int kbase = kk * 32 + ((l >> 4) << 3);
  bfrag_t pk;
#pragma unroll
  for (int j = 0; j < 8; ++j) pk[j] = (short)f2bf(W1[(size_t)(kbase + j) * 256 + h]);
  *(bfrag_t*)(W1f + (size_t)(bx * 64 + l) * 8) = pk;
}

__attribute__((amdgpu_flat_work_group_size(512, 512), amdgpu_waves_per_eu(2, 2)))
__global__ void attnpool_kernel(const float* __restrict__ x,
                                const int* __restrict__ batch,
                                const unsigned short* __restrict__ W1f,
                                const float* __restrict__ b1,
                                const float* __restrict__ W2,
                                const float* __restrict__ b2,
                                float* __restrict__ out,   // raw weighted sums (zeroed)
                                float* __restrict__ Zp,    // softmax denominator (zeroed)
                                int N, int base, int rem) {
  extern __shared__ char smem[];
  const int t = threadIdx.x;
  const int lane = t & 63;
  const int wv = t >> 6;
  const int l15 = lane & 15;
  const int hi = lane >> 4;

  char* xb = smem + wv * TILE_BYTES;   // this wave's private 32x256 bf16 tile

  const int slot = blockIdx.x * WPB + wv;
  const int cnt = base + (slot < rem ? 1 : 0);
  const int tile0 = slot * base + min(slot, rem);

  // per-wave constants in registers (read once; L2-hot)
  float b1v[16], w2v[16];
#pragma unroll
  for (int cc = 0; cc < 16; ++cc) {
    b1v[cc] = b1[cc * 16 + l15];
    w2v[cc] = W2[cc * 16 + l15];
  }
  const float b2c = b2[0];
  const bfrag_t* Wf = (const bfrag_t*)W1f;

  // staging: lane covers rows 2p+(lane>>5), col-octet soct=lane&31 (32B/lane/row)
  const int shalf = lane >> 5;
  const int soct = lane & 31;
  f32x4 st0[16], st1[16];   // raw staged tile (128 VGPR, live only around pool)

  auto stage_issue = [&](int tile) {
#pragma unroll
    for (int p = 0; p < 16; ++p) {
      const int row = 2 * p + shalf;
      int rg = tile * 32 + row;
      if (rg >= N) rg = N - 1;
      const float* s = x + (size_t)rg * 256 + soct * 8;
      st0[p] = *(const f32x4*)s;
      st1[p] = *(const f32x4*)(s + 4);
    }
  };
  auto stage_write = [&]() {
#pragma unroll
    for (int p = 0; p < 16; ++p) {
      const int row = 2 * p + shalf;
      *(bfrag_t*)(xb + row * 512 + ((soct * 16) ^ ((row & 7) << 4))) = pack8(st0[p], st1[p]);
    }
  };

  float zacc = 0.f;
  f32x4 pacc = {0.f, 0.f, 0.f, 0.f};
  int gcur = -1;

  auto flush = [&]() {
    float* po = out + (size_t)gcur * 256 + lane * 4;
    atomicAdd(po + 0, pacc[0]); atomicAdd(po + 1, pacc[1]);
    atomicAdd(po + 2, pacc[2]); atomicAdd(po + 3, pacc[3]);
    pacc[0] = pacc[1] = pacc[2] = pacc[3] = 0.f;
  };

  if (cnt > 0) { stage_issue(tile0); stage_write(); }

  for (int tt = 0; tt < cnt; ++tt) {
    const int tile = tile0 + tt;
    const int R0 = tile * 32;

    int bid;
    { int rg = min(R0 + (lane & 31), N - 1); bid = batch[rg]; }

    // ---- A-frags from swizzled LDS (rows l15 / 16+l15) ----
    bfrag_t A0[8], A1[8];
    {
      const int sw = (l15 & 7) << 4;
#pragma unroll
      for (int kk = 0; kk < 8; ++kk) {
        const int co = (kk * 64 + hi * 16) ^ sw;
        A0[kk] = *(const bfrag_t*)(xb + l15 * 512 + co);
        A1[kk] = *(const bfrag_t*)(xb + (16 + l15) * 512 + co);
      }
    }

    // ---- score: full-unrolled cc loop, B streamed from L2-resident W1f ----
    float s0v[4] = {0.f, 0.f, 0.f, 0.f};
    float s1v[4] = {0.f, 0.f, 0.f, 0.f};
#pragma unroll
    for (int cc = 0; cc < 16; ++cc) {
      f32x4 acc0 = {0.f, 0.f, 0.f, 0.f}, acc1 = {0.f, 0.f, 0.f, 0.f};
#pragma unroll
      for (int kk = 0; kk < 8; ++kk) {
        const bfrag_t Bk = Wf[(cc * 8 + kk) * 64 + lane];
        acc0 = __builtin_amdgcn_mfma_f32_16x16x32_bf16(A0[kk], Bk, acc0, 0, 0, 0);
        acc1 = __builtin_amdgcn_mfma_f32_16x16x32_bf16(A1[kk], Bk, acc1, 0, 0, 0);
      }
#pragma unroll
      for (int r = 0; r < 4; ++r) {
        s0v[r] += tanh_fast(acc0[r] + b1v[cc]) * w2v[cc];
        s1v[r] += tanh_fast(acc1[r] + b1v[cc]) * w2v[cc];
      }
    }

    // ---- softmax weights: reduce over l15; mask invalid rows; w = exp ----
    f32x4 w0v, w1v;
#pragma unroll
    for (int r = 0; r < 4; ++r) {
      float v0 = s0v[r], v1 = s1v[r];
      v0 += __shfl_xor(v0, 1); v0 += __shfl_xor(v0, 2);
      v0 += __shfl_xor(v0, 4); v0 += __shfl_xor(v0, 8);
      v1 += __shfl_xor(v1, 1); v1 += __shfl_xor(v1, 2);
      v1 += __shfl_xor(v1, 4); v1 += __shfl_xor(v1, 8);
      w0v[r] = (R0 + hi * 4 + r < N) ? __expf(v0 + b2c) : 0.f;
      w1v[r] = (R0 + 16 + hi * 4 + r < N) ? __expf(v1 + b2c) : 0.f;
    }
    {
      float z = w0v[0] + w0v[1] + w0v[2] + w0v[3] + w1v[0] + w1v[1] + w1v[2] + w1v[3];
      z += __shfl_xor(z, 16);
      z += __shfl_xor(z, 32);
      zacc += z;
    }

    // wlane: lane L (L=0..31) holds w[row L]. w0v[r]@group h = row h*4+r.
    float wlane;
    {
      const int rq = lane & 3;
      const float c0a = (rq == 0) ? w0v[0] : w0v[1];
      const float c0b = (rq == 2) ? w0v[2] : w0v[3];
      const float c0 = (rq < 2) ? c0a : c0b;
      const float c1a = (rq == 0) ? w1v[0] : w1v[1];
      const float c1b = (rq == 2) ? w1v[2] : w1v[3];
      const float c1 = (rq < 2) ? c1a : c1b;
      const int srcl = (((lane >> 2) & 3) << 4) + rq;   // group holding my row
      const float g0 = __shfl(c0, srcl);                // w[(lane&15)]
      const float g1 = __shfl(c1, srcl);                // w[16 + (lane&15)]
      wlane = ((lane & 31) < 16) ? g0 : g1;
    }

    // ---- T14 split: issue next tile's global loads; pool hides the latency ----
    if (tt + 1 < cnt) stage_issue(tile + 1);

    // ---- pool from swizzled LDS; lane owns cols 4*lane..+3 ----
    const int g_first = __builtin_amdgcn_readlane(bid, 0);
    const int g_last = __builtin_amdgcn_readlane(bid, 31);
    if (g_first != gcur) { if (gcur >= 0) flush(); gcur = g_first; }
    if (g_first == g_last) {
#pragma unroll
      for (int r = 0; r < 32; ++r) {
        const float wr = readlane_f(wlane, r);
        const u32x2 v = *(const u32x2*)(xb + r * 512 + ((lane * 8) ^ ((r & 7) << 4)));
        pacc[0] = __builtin_fmaf(wr, __uint_as_float(v[0] << 16), pacc[0]);
        pacc[1] = __builtin_fmaf(wr, __uint_as_float(v[0] & 0xffff0000u), pacc[1]);
        pacc[2] = __builtin_fmaf(wr, __uint_as_float(v[1] << 16), pacc[2]);
        pacc[3] = __builtin_fmaf(wr, __uint_as_float(v[1] & 0xffff0000u), pacc[3]);
      }
    } else {
      for (int r = 0; r < 32; ++r) {
        const int g = __builtin_amdgcn_readlane(bid, r);
        if (g != gcur) { flush(); gcur = g; }
        const float wr = readlane_f(wlane, r);
        const u32x2 v = *(const u32x2*)(xb + r * 512 + ((lane * 8) ^ ((r & 7) << 4)));
        pacc[0] = __builtin_fmaf(wr, __uint_as_float(v[0] << 16), pacc[0]);
        pacc[1] = __builtin_fmaf(wr, __uint_as_float(v[0] & 0xffff0000u), pacc[1]);
        pacc[2] = __builtin_fmaf(wr, __uint_as_float(v[1] << 16), pacc[2]);
        pacc[3] = __builtin_fmaf(wr, __uint_as_float(v[1] & 0xffff0000u), pacc[3]);
      }
    }

    // ---- finish stage: pool is done reading xb; overwrite with tile t+1 ----
    if (tt + 1 < cnt) stage_write();
  }

  if (gcur >= 0) flush();
  if (lane == 0 && zacc != 0.f) atomicAdd(Zp, zacc);
}

__global__ void finalize_kernel(float* __restrict__ out, const float* __restrict__ Zp, int n4) {
  const int i = blockIdx.x * blockDim.x + threadIdx.x;
  if (i < n4) {
    const float zi = 1.f / Zp[0];
    f32x4* p = (f32x4*)out;
    f32x4 v = p[i];
    v[0] *= zi; v[1] *= zi; v[2] *= zi; v[3] *= zi;
    p[i] = v;
  }
}

extern "C" void kernel_launch(void* const* d_in, const int* in_sizes, int n_in,
                              void* d_out, int out_size, void* d_ws, size_t ws_size,
                              hipStream_t stream) {
  const float* x  = (const float*)d_in[0];
  const int* batch = (const int*)d_in[1];
  const float* W1 = (const float*)d_in[2];
  const float* b1 = (const float*)d_in[3];
  const float* W2 = (const float*)d_in[4];
  const float* b2 = (const float*)d_in[5];
  float* out = (float*)d_out;
  const int N = in_sizes[1];

  unsigned short* W1f = (unsigned short*)d_ws;          // 128 KB
  float* Zp = (float*)((char*)d_ws + 131072);           // 4 B

  static int attr_done = 0;  // host-side only; idempotent attribute, not kernel state
  if (!attr_done) {
    hipFuncSetAttribute((const void*)attnpool_kernel,
                        hipFuncAttributeMaxDynamicSharedMemorySize, SMEM_BYTES);
    attr_done = 1;
  }

  const int ntiles = (N + 31) / 32;
  const int base = ntiles / SLOTS;
  const int rem = ntiles - base * SLOTS;

  hipMemsetAsync(d_out, 0, (size_t)out_size * sizeof(float), stream);
  hipMemsetAsync(Zp, 0, sizeof(float), stream);
  prep_w1_kernel<<<128, 64, 0, stream>>>(W1, W1f);
  attnpool_kernel<<<NBLOCKS, 512, SMEM_BYTES, stream>>>(x, batch, W1f, b1, W2, b2,
                                                        out, Zp, N, base, rem);
  finalize_kernel<<<(out_size / 4 + 255) / 256, 256, 0, stream>>>(out, Zp, out_size / 4);
}

// Round 11
// 647.799 us; speedup vs baseline: 1.3291x; 1.3291x over previous
//
#include <hip/hip_runtime.h>
#include <stdint.h>

#define NBLOCKS 256
#define WPB 4                          // waves per block (256 threads), 1 block/CU
#define SLOTS (NBLOCKS * WPB)          // 1024 independent wave slots
#define TILE_BYTES 32768               // 32 rows x 256 f32 = 32 KB
#define SMEM_BYTES (WPB * TILE_BYTES)  // 128 KB

typedef __attribute__((ext_vector_type(8))) short bfrag_t;
typedef __attribute__((ext_vector_type(4))) float f32x4;

static __device__ __forceinline__ unsigned short f2bf(float f) {
  unsigned int u = __float_as_uint(f);
  u += 0x7fffu + ((u >> 16) & 1u);   // RNE
  return (unsigned short)(u >> 16);
}

static __device__ __forceinline__ float tanh_fast(float s) {
  // tanh(s) = 1 - 2/(1+e^{2s}); saturates at +-1, no clamp needed
  float e = __builtin_exp2f(s * 2.8853900817779268f);
  float r = __builtin_amdgcn_rcpf(1.f + e);
  return __builtin_fmaf(-2.f, r, 1.f);
}

// readlane for floats: BIT-cast (int builtin; float would value-truncate — r4 bug)
static __device__ __forceinline__ float readlane_f(float v, int l) {
  return __uint_as_float(__builtin_amdgcn_readlane(__float_as_uint(v), l));
}

static __device__ __forceinline__ bfrag_t pack8(f32x4 a, f32x4 b) {
  union { bfrag_t v; unsigned int u[4]; } r;
  asm("v_cvt_pk_bf16_f32 %0, %1, %2" : "=v"(r.u[0]) : "v"(a[0]), "v"(a[1]));
  asm("v_cvt_pk_bf16_f32 %0, %1, %2" : "=v"(r.u[1]) : "v"(a[2]), "v"(a[3]));
  asm("v_cvt_pk_bf16_f32 %0, %1, %2" : "=v"(r.u[2]) : "v"(b[0]), "v"(b[1]));
  asm("v_cvt_pk_bf16_f32 %0, %1, %2" : "=v"(r.u[3]) : "v"(b[2]), "v"(b[3]));
  return r.v;
}

#define GLD16(gp, lp) __builtin_amdgcn_global_load_lds( \
    (const __attribute__((address_space(1))) void*)(gp), \
    (__attribute__((address_space(3))) void*)(lp), 16, 0, 0)

// wave-local waits; "memory" clobber orders the GLD16s / ds_reads around them,
// sched_barrier stops hipcc hoisting register-only work across (rule #18)
#define WAIT_VM0()   do { asm volatile("s_waitcnt vmcnt(0)" ::: "memory"); \
                          __builtin_amdgcn_sched_barrier(0); } while (0)
#define WAIT_LGKM0() do { asm volatile("s_waitcnt lgkmcnt(0)" ::: "memory"); \
                          __builtin_amdgcn_sched_barrier(0); } while (0)

// Pre-swizzle W1 (f32 [256][256], k-major) into MFMA B-fragment order, bf16.
// W1f[((cc*8+kk)*64 + lane)*8 + j] = bf16(W1[kk*32 + 8*(lane>>4) + j][cc*16 + (lane&15)])
__global__ void prep_w1_kernel(const float* __restrict__ W1, unsigned short* __restrict__ W1f) {
  const int bx = blockIdx.x;   // cc*8 + kk, 0..127
  const int l = threadIdx.x;   // 0..63
  const int cc = bx >> 3, kk = bx & 7;
  const int h = cc * 16 + (l & 15);
  const int kbase = kk * 32 + ((l >> 4) << 3);
  bfrag_t pk;
#pragma unroll
  for (int j = 0; j < 8; ++j) pk[j] = (short)f2bf(W1[(size_t)(kbase + j) * 256 + h]);
  *(bfrag_t*)(W1f + (size_t)(bx * 64 + l) * 8) = pk;
}

__attribute__((amdgpu_flat_work_group_size(256, 256), amdgpu_waves_per_eu(1, 1)))
__global__ void attnpool_kernel(const float* __restrict__ x,
                                const int* __restrict__ batch,
                                const unsigned short* __restrict__ W1f,
                                const float* __restrict__ b1,
                                const float* __restrict__ W2,
                                const float* __restrict__ b2,
                                float* __restrict__ out,   // raw weighted sums (zeroed)
                                float* __restrict__ Zp,    // softmax denominator (zeroed)
                                int N, int base, int rem) {
  extern __shared__ char smem[];
  const int t = threadIdx.x;
  const int lane = t & 63;
  const int wv = t >> 6;
  const int l15 = lane & 15;
  const int hi = lane >> 4;

  char* xb = smem + wv * TILE_BYTES;   // this wave's private 32x256 f32 tile

  const int slot = blockIdx.x * WPB + wv;
  const int cnt = base + (slot < rem ? 1 : 0);
  const int tile0 = slot * base + min(slot, rem);

  // per-wave constants in registers
  float b1v[16], w2v[16];
#pragma unroll
  for (int cc = 0; cc < 16; ++cc) {
    b1v[cc] = b1[cc * 16 + l15];
    w2v[cc] = W2[cc * 16 + l15];
  }
  const float b2c = b2[0];
  const bfrag_t* Wf = (const bfrag_t*)W1f;

  // stage: one GLD16 per row (64 lanes x 16B = 1KB = one f32 row).
  // Global source pre-swizzled so that logical byte c of row r lives at
  // physical r*1024 + (c ^ ((r&7)<<4))  [rule #21: linear dest, swz src+read]
  auto stage_issue = [&](int tile) {
    const size_t rbase = (size_t)tile * 32;
#pragma unroll
    for (int r = 0; r < 32; ++r) {
      const float* src = x + (rbase + r) * 256 + ((lane * 4) ^ ((r & 7) << 2));
      GLD16(src, xb + r * 1024);
    }
  };

  float zacc = 0.f;
  f32x4 pacc = {0.f, 0.f, 0.f, 0.f};
  int gcur = -1;

  auto flush = [&]() {
    float* po = out + (size_t)gcur * 256 + lane * 4;
    atomicAdd(po + 0, pacc[0]); atomicAdd(po + 1, pacc[1]);
    atomicAdd(po + 2, pacc[2]); atomicAdd(po + 3, pacc[3]);
    pacc[0] = pacc[1] = pacc[2] = pacc[3] = 0.f;
  };

  if (cnt > 0) stage_issue(tile0);

  for (int tt = 0; tt < cnt; ++tt) {
    const int tile = tile0 + tt;
    const int R0 = tile * 32;

    WAIT_VM0();   // wave-local: tile t fully landed in LDS

    int bid = batch[R0 + (lane & 31)];   // N % 32 == 0: always in range

    // ---- A-frags from swizzled f32 LDS -> bf16 regs (rows l15 / 16+l15) ----
    bfrag_t A0[8], A1[8];
    {
      const int sw = (l15 & 7) << 4;     // (16+l15)&7 == l15&7: same swizzle
      const char* r0p = xb + l15 * 1024;
      const char* r1p = xb + (16 + l15) * 1024;
#pragma unroll
      for (int kk = 0; kk < 8; ++kk) {
        const int c0 = kk * 128 + hi * 32;
        const f32x4 a0 = *(const f32x4*)(r0p + (c0 ^ sw));
        const f32x4 a1 = *(const f32x4*)(r0p + ((c0 + 16) ^ sw));
        const f32x4 b0 = *(const f32x4*)(r1p + (c0 ^ sw));
        const f32x4 b1f = *(const f32x4*)(r1p + ((c0 + 16) ^ sw));
        A0[kk] = pack8(a0, a1);
        A1[kk] = pack8(b0, b1f);
      }
    }

    // ---- score: full-unrolled cc loop, B streamed from L2-resident W1f ----
    float s0v[4] = {0.f, 0.f, 0.f, 0.f};
    float s1v[4] = {0.f, 0.f, 0.f, 0.f};
#pragma unroll
    for (int cc = 0; cc < 16; ++cc) {
      f32x4 acc0 = {0.f, 0.f, 0.f, 0.f}, acc1 = {0.f, 0.f, 0.f, 0.f};
#pragma unroll
      for (int kk = 0; kk < 8; ++kk) {
        const bfrag_t Bk = Wf[(cc * 8 + kk) * 64 + lane];
        acc0 = __builtin_amdgcn_mfma_f32_16x16x32_bf16(A0[kk], Bk, acc0, 0, 0, 0);
        acc1 = __builtin_amdgcn_mfma_f32_16x16x32_bf16(A1[kk], Bk, acc1, 0, 0, 0);
      }
#pragma unroll
      for (int r = 0; r < 4; ++r) {
        s0v[r] += tanh_fast(acc0[r] + b1v[cc]) * w2v[cc];
        s1v[r] += tanh_fast(acc1[r] + b1v[cc]) * w2v[cc];
      }
    }

    // ---- softmax weights: reduce over l15; w = exp(score + b2) ----
    f32x4 w0v, w1v;
#pragma unroll
    for (int r = 0; r < 4; ++r) {
      float v0 = s0v[r], v1 = s1v[r];
      v0 += __shfl_xor(v0, 1); v0 += __shfl_xor(v0, 2);
      v0 += __shfl_xor(v0, 4); v0 += __shfl_xor(v0, 8);
      v1 += __shfl_xor(v1, 1); v1 += __shfl_xor(v1, 2);
      v1 += __shfl_xor(v1, 4); v1 += __shfl_xor(v1, 8);
      w0v[r] = __expf(v0 + b2c);   // N % 32 == 0: all rows valid
      w1v[r] = __expf(v1 + b2c);
    }
    {
      float z = w0v[0] + w0v[1] + w0v[2] + w0v[3] + w1v[0] + w1v[1] + w1v[2] + w1v[3];
      z += __shfl_xor(z, 16);
      z += __shfl_xor(z, 32);
      zacc += z;
    }

    // wlane: lane L (L&31 = row) holds w[row]; w0v[r]@group h = row h*4+r
    float wlane;
    {
      const int rq = lane & 3;
      const float c0a = (rq == 0) ? w0v[0] : w0v[1];
      const float c0b = (rq == 2) ? w0v[2] : w0v[3];
      const float c0 = (rq < 2) ? c0a : c0b;
      const float c1a = (rq == 0) ? w1v[0] : w1v[1];
      const float c1b = (rq == 2) ? w1v[2] : w1v[3];
      const float c1 = (rq < 2) ? c1a : c1b;
      const int srcl = (((lane >> 2) & 3) << 4) + rq;   // group holding my row
      const float g0 = __shfl(c0, srcl);                // w[(lane&15)]
      const float g1 = __shfl(c1, srcl);                // w[16 + (lane&15)]
      wlane = ((lane & 31) < 16) ? g0 : g1;
    }

    // ---- pool from swizzled f32 LDS; lane owns cols 4*lane..+3 ----
    const int g_first = __builtin_amdgcn_readlane(bid, 0);
    const int g_last = __builtin_amdgcn_readlane(bid, 31);
    if (g_first != gcur) { if (gcur >= 0) flush(); gcur = g_first; }
    if (g_first == g_last) {
#pragma unroll
      for (int r = 0; r < 32; ++r) {
        const float wr = readlane_f(wlane, r);
        const f32x4 v = *(const f32x4*)(xb + r * 1024 + ((lane * 16) ^ ((r & 7) << 4)));
        pacc[0] = __builtin_fmaf(wr, v[0], pacc[0]);
        pacc[1] = __builtin_fmaf(wr, v[1], pacc[1]);
        pacc[2] = __builtin_fmaf(wr, v[2], pacc[2]);
        pacc[3] = __builtin_fmaf(wr, v[3], pacc[3]);
      }
    } else {
      for (int r = 0; r < 32; ++r) {
        const int g = __builtin_amdgcn_readlane(bid, r);
        if (g != gcur) { flush(); gcur = g; }
        const float wr = readlane_f(wlane, r);
        const f32x4 v = *(const f32x4*)(xb + r * 1024 + ((lane * 16) ^ ((r & 7) << 4)));
        pacc[0] = __builtin_fmaf(wr, v[0], pacc[0]);
        pacc[1] = __builtin_fmaf(wr, v[1], pacc[1]);
        pacc[2] = __builtin_fmaf(wr, v[2], pacc[2]);
        pacc[3] = __builtin_fmaf(wr, v[3], pacc[3]);
      }
    }

    // ---- drain DS reads, then overwrite the buffer with tile t+1 ----
    if (tt + 1 < cnt) {
      WAIT_LGKM0();
      stage_issue(tile + 1);
    }
  }

  if (gcur >= 0) flush();
  if (lane == 0 && zacc != 0.f) atomicAdd(Zp, zacc);
}

__global__ void finalize_kernel(float* __restrict__ out, const float* __restrict__ Zp, int n4) {
  const int i = blockIdx.x * blockDim.x + threadIdx.x;
  if (i < n4) {
    const float zi = 1.f / Zp[0];
    f32x4* p = (f32x4*)out;
    f32x4 v = p[i];
    v[0] *= zi; v[1] *= zi; v[2] *= zi; v[3] *= zi;
    p[i] = v;
  }
}

extern "C" void kernel_launch(void* const* d_in, const int* in_sizes, int n_in,
                              void* d_out, int out_size, void* d_ws, size_t ws_size,
                              hipStream_t stream) {
  const float* x  = (const float*)d_in[0];
  const int* batch = (const int*)d_in[1];
  const float* W1 = (const float*)d_in[2];
  const float* b1 = (const float*)d_in[3];
  const float* W2 = (const float*)d_in[4];
  const float* b2 = (const float*)d_in[5];
  float* out = (float*)d_out;
  const int N = in_sizes[1];

  unsigned short* W1f = (unsigned short*)d_ws;          // 128 KB
  float* Zp = (float*)((char*)d_ws + 131072);           // 4 B

  static int attr_done = 0;  // host-side only; idempotent attribute, not kernel state
  if (!attr_done) {
    hipFuncSetAttribute((const void*)attnpool_kernel,
                        hipFuncAttributeMaxDynamicSharedMemorySize, SMEM_BYTES);
    attr_done = 1;
  }

  const int ntiles = (N + 31) / 32;
  const int base = ntiles / SLOTS;
  const int rem = ntiles - base * SLOTS;

  hipMemsetAsync(d_out, 0, (size_t)out_size * sizeof(float), stream);
  hipMemsetAsync(Zp, 0, sizeof(float), stream);
  prep_w1_kernel<<<128, 64, 0, stream>>>(W1, W1f);
  attnpool_kernel<<<NBLOCKS, 256, SMEM_BYTES, stream>>>(x, batch, W1f, b1, W2, b2,
                                                        out, Zp, N, base, rem);
  finalize_kernel<<<(out_size / 4 + 255) / 256, 256, 0, stream>>>(out, Zp, out_size / 4);
}

// Round 12
// 192.125 us; speedup vs baseline: 4.4814x; 3.3718x over previous
//
#include <hip/hip_runtime.h>
#include <stdint.h>

#define NBLOCKS 256
#define TROWS 64                         // rows per block-tile
#define SMEM_BYTES (131072 + TROWS * 512)  // 128KB B-frags + 32KB bf16 x-tile = 160KB

typedef __attribute__((ext_vector_type(8))) short bfrag_t;
typedef __attribute__((ext_vector_type(4))) float f32x4;
typedef __attribute__((ext_vector_type(2))) unsigned int u32x2;

static __device__ __forceinline__ unsigned short f2bf(float f) {
  unsigned int u = __float_as_uint(f);
  u += 0x7fffu + ((u >> 16) & 1u);   // RNE
  return (unsigned short)(u >> 16);
}

static __device__ __forceinline__ float tanh_fast(float s) {
  // tanh(s) = 1 - 2/(1+e^{2s}); saturates at +-1, no clamp needed
  float e = __builtin_exp2f(s * 2.8853900817779268f);
  float r = __builtin_amdgcn_rcpf(1.f + e);
  return __builtin_fmaf(-2.f, r, 1.f);
}

// readlane for floats: BIT-cast (int builtin; float would value-truncate — r4 bug)
static __device__ __forceinline__ float readlane_f(float v, int l) {
  return __uint_as_float(__builtin_amdgcn_readlane(__float_as_uint(v), l));
}

static __device__ __forceinline__ bfrag_t pack8(f32x4 a, f32x4 b) {
  union { bfrag_t v; unsigned int u[4]; } r;
  asm("v_cvt_pk_bf16_f32 %0, %1, %2" : "=v"(r.u[0]) : "v"(a[0]), "v"(a[1]));
  asm("v_cvt_pk_bf16_f32 %0, %1, %2" : "=v"(r.u[1]) : "v"(a[2]), "v"(a[3]));
  asm("v_cvt_pk_bf16_f32 %0, %1, %2" : "=v"(r.u[2]) : "v"(b[0]), "v"(b[1]));
  asm("v_cvt_pk_bf16_f32 %0, %1, %2" : "=v"(r.u[3]) : "v"(b[2]), "v"(b[3]));
  return r.v;
}

#define GLD16(gp, lp) __builtin_amdgcn_global_load_lds( \
    (const __attribute__((address_space(1))) void*)(gp), \
    (__attribute__((address_space(3))) void*)(lp), 16, 0, 0)

// Pre-swizzle W1 (f32 [256][256], k-major) into MFMA B-fragment order, bf16.
// W1f[((cc*8+kk)*64 + lane)*8 + j] = bf16(W1[kk*32 + 8*(lane>>4) + j][cc*16 + (lane&15)])
__global__ void prep_w1_kernel(const float* __restrict__ W1, unsigned short* __restrict__ W1f) {
  const int bx = blockIdx.x;   // cc*8 + kk, 0..127
  const int l = threadIdx.x;   // 0..63
  const int cc = bx >> 3, kk = bx & 7;
  const int h = cc * 16 + (l & 15);
  const int kbase = kk * 32 + ((l >> 4) << 3);
  bfrag_t pk;
#pragma unroll
  for (int j = 0; j < 8; ++j) pk[j] = (short)f2bf(W1[(size_t)(kbase + j) * 256 + h]);
  *(bfrag_t*)(W1f + (size_t)(bx * 64 + l) * 8) = pk;
}

__attribute__((amdgpu_flat_work_group_size(256, 256), amdgpu_waves_per_eu(1, 1)))
__global__ void attnpool_kernel(const float* __restrict__ x,
                                const int* __restrict__ batch,
                                const unsigned short* __restrict__ W1f,
                                const float* __restrict__ b1,
                                const float* __restrict__ W2,
                                const float* __restrict__ b2,
                                float* __restrict__ out,   // raw weighted sums (zeroed)
                                float* __restrict__ Zp,    // softmax denominator (zeroed)
                                int N, int base, int rem) {
  extern __shared__ char smem[];
  char* Bl = smem;               // [128 frags][64 lanes][16B] frag-linear B
  char* xt = smem + 131072;      // [64 rows][512B] bf16 x-tile, XOR-swizzled

  const int t = threadIdx.x;
  const int lane = t & 63;
  const int wv = t >> 6;
  const int l15 = lane & 15;
  const int hi = lane >> 4;

  const int blk = blockIdx.x;
  const int cnt = base + (blk < rem ? 1 : 0);
  const int tile0 = blk * base + min(blk, rem);

  // ---- B -> LDS (frag-linear, GLD16; zero registers) ----
#pragma unroll
  for (int i = 0; i < 32; ++i) {
    const int f = wv * 32 + i;
    GLD16(W1f + (size_t)f * 512 + lane * 8, Bl + f * 1024);
  }

  // per-lane constants
  float b1v[16], w2v[16];
#pragma unroll
  for (int cc = 0; cc < 16; ++cc) {
    b1v[cc] = b1[cc * 16 + l15];
    w2v[cc] = W2[cc * 16 + l15];
  }
  const float b2c = b2[0];

  // ---- cooperative T14 reg-staging: 256 threads stage 64 rows ----
  // thread t: rows p*8 + (t>>5), col-octet (t&31)*8 floats (32B) -> 16 f32x4 regs
  const int srow = t >> 5;
  const int soct = t & 31;
  f32x4 sreg[16];
  auto issue_loads = [&](int tile) {
#pragma unroll
    for (int p = 0; p < 8; ++p) {
      const int row = p * 8 + srow;
      const int rg = min(tile * TROWS + row, N - 1);
      const float* s = x + (size_t)rg * 256 + soct * 8;
      sreg[2 * p] = *(const f32x4*)s;
      sreg[2 * p + 1] = *(const f32x4*)(s + 4);
    }
  };
  auto write_tile = [&]() {
#pragma unroll
    for (int p = 0; p < 8; ++p) {
      const int row = p * 8 + srow;
      *(bfrag_t*)(xt + row * 512 + ((soct * 16) ^ ((row & 7) << 4))) =
          pack8(sreg[2 * p], sreg[2 * p + 1]);
    }
  };

  issue_loads(tile0);
  write_tile();
  __syncthreads();   // B staged + tile0 visible

  float zacc = 0.f;
  f32x4 pacc = {0.f, 0.f, 0.f, 0.f};
  int gcur = -1;

  auto flush = [&]() {
    float* po = out + (size_t)gcur * 256 + lane * 4;
    atomicAdd(po + 0, pacc[0]); atomicAdd(po + 1, pacc[1]);
    atomicAdd(po + 2, pacc[2]); atomicAdd(po + 3, pacc[3]);
    pacc[0] = pacc[1] = pacc[2] = pacc[3] = 0.f;
  };

  for (int tt = 0; tt < cnt; ++tt) {
    const int tile = tile0 + tt;
    const int R0 = tile * TROWS;

    // issue next tile's global loads first: in flight across score+pool
    if (tt + 1 < cnt) issue_loads(tile + 1);

    // ---- A-frags (bf16, direct from LDS): wave wv owns rows wv*16..+15 ----
    bfrag_t A0[8];
    {
      const int arow = wv * 16 + l15;
      const int sw = (l15 & 7) << 4;
      const char* ap = xt + arow * 512;
#pragma unroll
      for (int kk = 0; kk < 8; ++kk)
        A0[kk] = *(const bfrag_t*)(ap + ((kk * 64 + hi * 16) ^ sw));
    }

    // ---- score: B from LDS (lane-linear, conflict-free) ----
    float s0v[4] = {0.f, 0.f, 0.f, 0.f};
#pragma unroll
    for (int cc = 0; cc < 16; ++cc) {
      f32x4 acc = {0.f, 0.f, 0.f, 0.f};
#pragma unroll
      for (int kk = 0; kk < 8; ++kk) {
        const bfrag_t Bk = *(const bfrag_t*)(Bl + (cc * 8 + kk) * 1024 + lane * 16);
        acc = __builtin_amdgcn_mfma_f32_16x16x32_bf16(A0[kk], Bk, acc, 0, 0, 0);
      }
#pragma unroll
      for (int r = 0; r < 4; ++r)
        s0v[r] += tanh_fast(acc[r] + b1v[cc]) * w2v[cc];
    }

    // ---- weights: reduce over l15; row = wv*16 + hi*4 + r ----
    f32x4 w0v;
#pragma unroll
    for (int r = 0; r < 4; ++r) {
      float v = s0v[r];
      v += __shfl_xor(v, 1); v += __shfl_xor(v, 2);
      v += __shfl_xor(v, 4); v += __shfl_xor(v, 8);
      w0v[r] = (R0 + wv * 16 + hi * 4 + r < N) ? __expf(v + b2c) : 0.f;
    }
    {
      float z = w0v[0] + w0v[1] + w0v[2] + w0v[3];
      z += __shfl_xor(z, 16);
      z += __shfl_xor(z, 32);
      zacc += z;   // sum of this wave's 16 row-weights
    }

    // wlane: lane L holds w[L&15] (this wave's rows)
    float wlane;
    {
      const int rq = lane & 3;
      const float ca = (rq == 0) ? w0v[0] : w0v[1];
      const float cb = (rq == 2) ? w0v[2] : w0v[3];
      const float c = (rq < 2) ? ca : cb;
      const int srcl = (((lane >> 2) & 3) << 4) + rq;
      wlane = __shfl(c, srcl);
    }

    // batch ids for this wave's 16 rows
    int bid = batch[min(R0 + wv * 16 + l15, N - 1)];

    // ---- pool this wave's 16 rows; lane owns bf16 cols 4*lane..+3 ----
    const int g_first = __builtin_amdgcn_readlane(bid, 0);
    const int g_last = __builtin_amdgcn_readlane(bid, 15);
    if (g_first != gcur) { if (gcur >= 0) flush(); gcur = g_first; }
    const int rowb = wv * 16;
    if (g_first == g_last) {
#pragma unroll
      for (int r = 0; r < 16; ++r) {
        const float wr = readlane_f(wlane, r);
        const int row = rowb + r;
        const u32x2 v = *(const u32x2*)(xt + row * 512 + ((lane * 8) ^ ((row & 7) << 4)));
        pacc[0] = __builtin_fmaf(wr, __uint_as_float(v[0] << 16), pacc[0]);
        pacc[1] = __builtin_fmaf(wr, __uint_as_float(v[0] & 0xffff0000u), pacc[1]);
        pacc[2] = __builtin_fmaf(wr, __uint_as_float(v[1] << 16), pacc[2]);
        pacc[3] = __builtin_fmaf(wr, __uint_as_float(v[1] & 0xffff0000u), pacc[3]);
      }
    } else {
      for (int r = 0; r < 16; ++r) {
        const int g = __builtin_amdgcn_readlane(bid, r);
        if (g != gcur) { flush(); gcur = g; }
        const float wr = readlane_f(wlane, r);
        const int row = rowb + r;
        const u32x2 v = *(const u32x2*)(xt + row * 512 + ((lane * 8) ^ ((row & 7) << 4)));
        pacc[0] = __builtin_fmaf(wr, __uint_as_float(v[0] << 16), pacc[0]);
        pacc[1] = __builtin_fmaf(wr, __uint_as_float(v[0] & 0xffff0000u), pacc[1]);
        pacc[2] = __builtin_fmaf(wr, __uint_as_float(v[1] << 16), pacc[2]);
        pacc[3] = __builtin_fmaf(wr, __uint_as_float(v[1] & 0xffff0000u), pacc[3]);
      }
    }

    __syncthreads();                    // all waves done reading tile t (drains loads)
    if (tt + 1 < cnt) write_tile();     // cvt + ds_write tile t+1
    __syncthreads();                    // tile t+1 visible
  }

  if (gcur >= 0) flush();
  if (lane == 0 && zacc != 0.f) atomicAdd(Zp, zacc);
}

__global__ void finalize_kernel(float* __restrict__ out, const float* __restrict__ Zp, int n4) {
  const int i = blockIdx.x * blockDim.x + threadIdx.x;
  if (i < n4) {
    const float zi = 1.f / Zp[0];
    f32x4* p = (f32x4*)out;
    f32x4 v = p[i];
    v[0] *= zi; v[1] *= zi; v[2] *= zi; v[3] *= zi;
    p[i] = v;
  }
}

extern "C" void kernel_launch(void* const* d_in, const int* in_sizes, int n_in,
                              void* d_out, int out_size, void* d_ws, size_t ws_size,
                              hipStream_t stream) {
  const float* x  = (const float*)d_in[0];
  const int* batch = (const int*)d_in[1];
  const float* W1 = (const float*)d_in[2];
  const float* b1 = (const float*)d_in[3];
  const float* W2 = (const float*)d_in[4];
  const float* b2 = (const float*)d_in[5];
  float* out = (float*)d_out;
  const int N = in_sizes[1];

  unsigned short* W1f = (unsigned short*)d_ws;          // 128 KB
  float* Zp = (float*)((char*)d_ws + 131072);           // 4 B

  static int attr_done = 0;  // host-side only; idempotent attribute, not kernel state
  if (!attr_done) {
    hipFuncSetAttribute((const void*)attnpool_kernel,
                        hipFuncAttributeMaxDynamicSharedMemorySize, SMEM_BYTES);
    attr_done = 1;
  }

  const int ntiles = (N + TROWS - 1) / TROWS;
  const int base = ntiles / NBLOCKS;
  const int rem = ntiles % NBLOCKS;

  hipMemsetAsync(d_out, 0, (size_t)out_size * sizeof(float), stream);
  hipMemsetAsync(Zp, 0, sizeof(float), stream);
  prep_w1_kernel<<<128, 64, 0, stream>>>(W1, W1f);
  attnpool_kernel<<<NBLOCKS, 256, SMEM_BYTES, stream>>>(x, batch, W1f, b1, W2, b2,
                                                        out, Zp, N, base, rem);
  finalize_kernel<<<(out_size / 4 + 255) / 256, 256, 0, stream>>>(out, Zp, out_size / 4);
}

// Round 13
// 178.924 us; speedup vs baseline: 4.8120x; 1.0738x over previous
//
#include <hip/hip_runtime.h>
#include <stdint.h>

#define NBLOCKS 256
#define TROWS 64
#define B_FRAGS 127                       // frag 127 streamed from L2 (LDS carve-out)
#define XT_OFF (B_FRAGS * 1024)           // 130048
#define SPART_OFF (XT_OFF + TROWS * 512)  // 162816
#define SMEM_BYTES (SPART_OFF + 512)      // 163328 <= 163840

typedef __attribute__((ext_vector_type(8))) short bfrag_t;
typedef __attribute__((ext_vector_type(4))) float f32x4;
typedef __attribute__((ext_vector_type(2))) unsigned int u32x2;

static __device__ __forceinline__ unsigned short f2bf(float f) {
  unsigned int u = __float_as_uint(f);
  u += 0x7fffu + ((u >> 16) & 1u);   // RNE
  return (unsigned short)(u >> 16);
}

static __device__ __forceinline__ float tanh_fast(float s) {
  // tanh(s) = 1 - 2/(1+e^{2s}); saturates at +-1, no clamp needed
  float e = __builtin_exp2f(s * 2.8853900817779268f);
  float r = __builtin_amdgcn_rcpf(1.f + e);
  return __builtin_fmaf(-2.f, r, 1.f);
}

// readlane for floats: BIT-cast (int builtin; float would value-truncate — r4 bug)
static __device__ __forceinline__ float readlane_f(float v, int l) {
  return __uint_as_float(__builtin_amdgcn_readlane(__float_as_uint(v), l));
}

static __device__ __forceinline__ bfrag_t pack8(f32x4 a, f32x4 b) {
  union { bfrag_t v; unsigned int u[4]; } r;
  asm("v_cvt_pk_bf16_f32 %0, %1, %2" : "=v"(r.u[0]) : "v"(a[0]), "v"(a[1]));
  asm("v_cvt_pk_bf16_f32 %0, %1, %2" : "=v"(r.u[1]) : "v"(a[2]), "v"(a[3]));
  asm("v_cvt_pk_bf16_f32 %0, %1, %2" : "=v"(r.u[2]) : "v"(b[0]), "v"(b[1]));
  asm("v_cvt_pk_bf16_f32 %0, %1, %2" : "=v"(r.u[3]) : "v"(b[2]), "v"(b[3]));
  return r.v;
}

#define GLD16(gp, lp) __builtin_amdgcn_global_load_lds( \
    (const __attribute__((address_space(1))) void*)(gp), \
    (__attribute__((address_space(3))) void*)(lp), 16, 0, 0)

// Pre-swizzle W1 (f32 [256][256], k-major) into MFMA B-fragment order, bf16.
// W1f[((cc*8+kk)*64 + lane)*8 + j] = bf16(W1[kk*32 + 8*(lane>>4) + j][cc*16 + (lane&15)])
__global__ void prep_w1_kernel(const float* __restrict__ W1, unsigned short* __restrict__ W1f) {
  const int bx = blockIdx.x;   // cc*8 + kk, 0..127
  const int l = threadIdx.x;   // 0..63
  const int cc = bx >> 3, kk = bx & 7;
  const int h = cc * 16 + (l & 15);
  const int kbase = kk * 32 + ((l >> 4) << 3);
  bfrag_t pk;
#pragma unroll
  for (int j = 0; j < 8; ++j) pk[j] = (short)f2bf(W1[(size_t)(kbase + j) * 256 + h]);
  *(bfrag_t*)(W1f + (size_t)(bx * 64 + l) * 8) = pk;
}

__attribute__((amdgpu_flat_work_group_size(512, 512), amdgpu_waves_per_eu(2, 2)))
__global__ void attnpool_kernel(const float* __restrict__ x,
                                const int* __restrict__ batch,
                                const unsigned short* __restrict__ W1f,
                                const float* __restrict__ b1,
                                const float* __restrict__ W2,
                                const float* __restrict__ b2,
                                float* __restrict__ out,   // raw weighted sums (zeroed)
                                float* __restrict__ Zp,    // softmax denominator (zeroed)
                                int N, int base, int rem) {
  extern __shared__ char smem[];
  char* Bl = smem;                           // B frags 0..126, frag-linear
  char* xt = smem + XT_OFF;                  // [64 rows][512B] bf16 tile, swizzled
  float* spart = (float*)(smem + SPART_OFF); // [2 cg][64 rows] score partials

  const int t = threadIdx.x;
  const int lane = t & 63;
  const int wv = t >> 6;        // 0..7
  const int rg = wv & 3;        // row group: rows rg*16..+15
  const int cg = wv >> 2;       // cc group: cc cg*8..+7
  const int l15 = lane & 15;
  const int hi = lane >> 4;

  const int blk = blockIdx.x;
  const int cnt = base + (blk < rem ? 1 : 0);
  const int tile0 = blk * base + min(blk, rem);

  // ---- B -> LDS (frag-linear, GLD16; zero registers). frag 127 stays in L2 ----
#pragma unroll
  for (int i = 0; i < 16; ++i) {
    const int f = wv * 16 + i;
    if (f < B_FRAGS) GLD16(W1f + (size_t)f * 512 + lane * 8, Bl + f * 1024);
  }

  // per-lane constants for my 8 cc's
  float b1v[8], w2v[8];
#pragma unroll
  for (int i = 0; i < 8; ++i) {
    b1v[i] = b1[(cg * 8 + i) * 16 + l15];
    w2v[i] = W2[(cg * 8 + i) * 16 + l15];
  }
  const float b2c = b2[0];

  // ---- cooperative T14 reg-staging: 512 threads stage 64 rows ----
  const int srow = t >> 5;    // 0..15
  const int soct = t & 31;
  f32x4 sreg[8];
  auto issue_loads = [&](int tile) {
#pragma unroll
    for (int p = 0; p < 4; ++p) {
      const int row = p * 16 + srow;
      const int rgb = min(tile * TROWS + row, N - 1);
      const float* s = x + (size_t)rgb * 256 + soct * 8;
      sreg[2 * p] = *(const f32x4*)s;
      sreg[2 * p + 1] = *(const f32x4*)(s + 4);
    }
  };
  auto write_tile = [&]() {
#pragma unroll
    for (int p = 0; p < 4; ++p) {
      const int row = p * 16 + srow;
      *(bfrag_t*)(xt + row * 512 + ((soct * 16) ^ ((row & 7) << 4))) =
          pack8(sreg[2 * p], sreg[2 * p + 1]);
    }
  };

  issue_loads(tile0);
  write_tile();
  __syncthreads();   // B + tile0 staged

  float zacc = 0.f;
  f32x4 pacc = {0.f, 0.f, 0.f, 0.f};
  int gcur = -1;

  auto flush = [&]() {
    float* po = out + (size_t)gcur * 256 + lane * 4;
    atomicAdd(po + 0, pacc[0]); atomicAdd(po + 1, pacc[1]);
    atomicAdd(po + 2, pacc[2]); atomicAdd(po + 3, pacc[3]);
    pacc[0] = pacc[1] = pacc[2] = pacc[3] = 0.f;
  };

  for (int tt = 0; tt < cnt; ++tt) {
    const int tile = tile0 + tt;
    const int R0 = tile * TROWS;

    if (tt + 1 < cnt) issue_loads(tile + 1);   // in flight across score+pool

    // ---- A-frags: rows rg*16..+15 from swizzled LDS ----
    bfrag_t A0[8];
    {
      const int arow = rg * 16 + l15;
      const int sw = (l15 & 7) << 4;
      const char* ap = xt + arow * 512;
#pragma unroll
      for (int kk = 0; kk < 8; ++kk)
        A0[kk] = *(const bfrag_t*)(ap + ((kk * 64 + hi * 16) ^ sw));
    }

    // ---- partial score over my 8 cc's ----
    float s0v[4] = {0.f, 0.f, 0.f, 0.f};
#pragma unroll
    for (int i = 0; i < 8; ++i) {
      const int cc = cg * 8 + i;
      f32x4 acc = {0.f, 0.f, 0.f, 0.f};
#pragma unroll
      for (int kk = 0; kk < 8; ++kk) {
        const int frag = cc * 8 + kk;
        bfrag_t Bk;
        if (frag == B_FRAGS)   // wave-uniform; only (cg=1,i=7,kk=7)
          Bk = *(const bfrag_t*)(W1f + (size_t)frag * 512 + lane * 8);
        else
          Bk = *(const bfrag_t*)(Bl + frag * 1024 + lane * 16);
        acc = __builtin_amdgcn_mfma_f32_16x16x32_bf16(A0[kk], Bk, acc, 0, 0, 0);
      }
#pragma unroll
      for (int r = 0; r < 4; ++r)
        s0v[r] += tanh_fast(acc[r] + b1v[i]) * w2v[i];
    }

    // reduce over l15 (all lanes get row-partial for row rg*16+hi*4+r)
#pragma unroll
    for (int r = 0; r < 4; ++r) {
      float v = s0v[r];
      v += __shfl_xor(v, 1); v += __shfl_xor(v, 2);
      v += __shfl_xor(v, 4); v += __shfl_xor(v, 8);
      s0v[r] = v;
    }
    if (l15 == 0) {
#pragma unroll
      for (int r = 0; r < 4; ++r)
        spart[cg * 64 + rg * 16 + hi * 4 + r] = s0v[r];
    }
    __syncthreads();   // SYNC1: both partials visible

    // ---- combine partner partial, exp; both partner waves compute all 16 w ----
    f32x4 w0v;
#pragma unroll
    for (int r = 0; r < 4; ++r) {
      const int row = rg * 16 + hi * 4 + r;
      const float s = s0v[r] + spart[(cg ^ 1) * 64 + row] + b2c;
      w0v[r] = (R0 + row < N) ? __expf(s) : 0.f;
    }
    if (cg == 0) {   // count each row's z exactly once
      float z = w0v[0] + w0v[1] + w0v[2] + w0v[3];
      z += __shfl_xor(z, 16);
      z += __shfl_xor(z, 32);
      zacc += z;
    }

    // wlane: lane L holds w[rg*16 + (L&15)]
    float wlane;
    {
      const int rq = lane & 3;
      const float ca = (rq == 0) ? w0v[0] : w0v[1];
      const float cb = (rq == 2) ? w0v[2] : w0v[3];
      const float c = (rq < 2) ? ca : cb;
      const int srcl = (((lane >> 2) & 3) << 4) + rq;
      wlane = __shfl(c, srcl);
    }

    int bid = batch[min(R0 + rg * 16 + l15, N - 1)];

    // ---- pool my half (8 rows: rg*16 + cg*8 .. +8); lane owns cols 4*lane..+3 ----
    const int g_first = __builtin_amdgcn_readlane(bid, cg * 8);
    const int g_last = __builtin_amdgcn_readlane(bid, cg * 8 + 7);
    if (g_first != gcur) { if (gcur >= 0) flush(); gcur = g_first; }
    const int rowb = rg * 16 + cg * 8;
    if (g_first == g_last) {
#pragma unroll
      for (int r = 0; r < 8; ++r) {
        const float wr = readlane_f(wlane, cg * 8 + r);
        const int row = rowb + r;
        const u32x2 v = *(const u32x2*)(xt + row * 512 + ((lane * 8) ^ ((row & 7) << 4)));
        pacc[0] = __builtin_fmaf(wr, __uint_as_float(v[0] << 16), pacc[0]);
        pacc[1] = __builtin_fmaf(wr, __uint_as_float(v[0] & 0xffff0000u), pacc[1]);
        pacc[2] = __builtin_fmaf(wr, __uint_as_float(v[1] << 16), pacc[2]);
        pacc[3] = __builtin_fmaf(wr, __uint_as_float(v[1] & 0xffff0000u), pacc[3]);
      }
    } else {
      for (int r = 0; r < 8; ++r) {
        const int g = __builtin_amdgcn_readlane(bid, cg * 8 + r);
        if (g != gcur) { flush(); gcur = g; }
        const float wr = readlane_f(wlane, cg * 8 + r);
        const int row = rowb + r;
        const u32x2 v = *(const u32x2*)(xt + row * 512 + ((lane * 8) ^ ((row & 7) << 4)));
        pacc[0] = __builtin_fmaf(wr, __uint_as_float(v[0] << 16), pacc[0]);
        pacc[1] = __builtin_fmaf(wr, __uint_as_float(v[0] & 0xffff0000u), pacc[1]);
        pacc[2] = __builtin_fmaf(wr, __uint_as_float(v[1] << 16), pacc[2]);
        pacc[3] = __builtin_fmaf(wr, __uint_as_float(v[1] & 0xffff0000u), pacc[3]);
      }
    }

    __syncthreads();                    // SYNC2: all reads of tile t done
    if (tt + 1 < cnt) write_tile();     // cvt + ds_write tile t+1
    __syncthreads();                    // SYNC3: tile t+1 visible
  }

  if (gcur >= 0) flush();
  if (lane == 0 && zacc != 0.f) atomicAdd(Zp, zacc);
}

__global__ void finalize_kernel(float* __restrict__ out, const float* __restrict__ Zp, int n4) {
  const int i = blockIdx.x * blockDim.x + threadIdx.x;
  if (i < n4) {
    const float zi = 1.f / Zp[0];
    f32x4* p = (f32x4*)out;
    f32x4 v = p[i];
    v[0] *= zi; v[1] *= zi; v[2] *= zi; v[3] *= zi;
    p[i] = v;
  }
}

extern "C" void kernel_launch(void* const* d_in, const int* in_sizes, int n_in,
                              void* d_out, int out_size, void* d_ws, size_t ws_size,
                              hipStream_t stream) {
  const float* x  = (const float*)d_in[0];
  const int* batch = (const int*)d_in[1];
  const float* W1 = (const float*)d_in[2];
  const float* b1 = (const float*)d_in[3];
  const float* W2 = (const float*)d_in[4];
  const float* b2 = (const float*)d_in[5];
  float* out = (float*)d_out;
  const int N = in_sizes[1];

  unsigned short* W1f = (unsigned short*)d_ws;          // 128 KB
  float* Zp = (float*)((char*)d_ws + 131072);           // 4 B

  static int attr_done = 0;  // host-side only; idempotent attribute, not kernel state
  if (!attr_done) {
    hipFuncSetAttribute((const void*)attnpool_kernel,
                        hipFuncAttributeMaxDynamicSharedMemorySize, SMEM_BYTES);
    attr_done = 1;
  }

  const int ntiles = (N + TROWS - 1) / TROWS;
  const int base = ntiles / NBLOCKS;
  const int rem = ntiles % NBLOCKS;

  hipMemsetAsync(d_out, 0, (size_t)out_size * sizeof(float), stream);
  hipMemsetAsync(Zp, 0, sizeof(float), stream);
  prep_w1_kernel<<<128, 64, 0, stream>>>(W1, W1f);
  attnpool_kernel<<<NBLOCKS, 512, SMEM_BYTES, stream>>>(x, batch, W1f, b1, W2, b2,
                                                        out, Zp, N, base, rem);
  finalize_kernel<<<(out_size / 4 + 255) / 256, 256, 0, stream>>>(out, Zp, out_size / 4);
}

// Round 14
// 175.491 us; speedup vs baseline: 4.9061x; 1.0196x over previous
//
#include <hip/hip_runtime.h>
#include <stdint.h>

#define NBLOCKS 256
#define TROWS 64
#define B_FRAGS 127                       // frag 127 streamed from L2 (LDS carve-out)
#define XT_OFF (B_FRAGS * 1024)           // 130048
#define SPART_OFF (XT_OFF + TROWS * 512)  // 162816
#define SMEM_BYTES (SPART_OFF + 512)      // 163328 <= 163840

typedef __attribute__((ext_vector_type(8))) short bfrag_t;
typedef __attribute__((ext_vector_type(4))) float f32x4;
typedef __attribute__((ext_vector_type(2))) unsigned int u32x2;

static __device__ __forceinline__ unsigned short f2bf(float f) {
  unsigned int u = __float_as_uint(f);
  u += 0x7fffu + ((u >> 16) & 1u);   // RNE
  return (unsigned short)(u >> 16);
}

static __device__ __forceinline__ float tanh_fast(float s) {
  // tanh(s) = 1 - 2/(1+e^{2s}); saturates at +-1, no clamp needed
  float e = __builtin_exp2f(s * 2.8853900817779268f);
  float r = __builtin_amdgcn_rcpf(1.f + e);
  return __builtin_fmaf(-2.f, r, 1.f);
}

// readlane for floats: BIT-cast (int builtin; float would value-truncate — r4 bug)
static __device__ __forceinline__ float readlane_f(float v, int l) {
  return __uint_as_float(__builtin_amdgcn_readlane(__float_as_uint(v), l));
}

static __device__ __forceinline__ bfrag_t pack8(f32x4 a, f32x4 b) {
  union { bfrag_t v; unsigned int u[4]; } r;
  asm("v_cvt_pk_bf16_f32 %0, %1, %2" : "=v"(r.u[0]) : "v"(a[0]), "v"(a[1]));
  asm("v_cvt_pk_bf16_f32 %0, %1, %2" : "=v"(r.u[1]) : "v"(a[2]), "v"(a[3]));
  asm("v_cvt_pk_bf16_f32 %0, %1, %2" : "=v"(r.u[2]) : "v"(b[0]), "v"(b[1]));
  asm("v_cvt_pk_bf16_f32 %0, %1, %2" : "=v"(r.u[3]) : "v"(b[2]), "v"(b[3]));
  return r.v;
}

#define GLD16(gp, lp) __builtin_amdgcn_global_load_lds( \
    (const __attribute__((address_space(1))) void*)(gp), \
    (__attribute__((address_space(3))) void*)(lp), 16, 0, 0)

// raw barrier: drain LDS ops only (lgkmcnt), leave global reg-loads in flight.
// "memory" clobbers stop compiler-level reordering of LDS accesses across it.
#define BAR_LGKM() do { \
  asm volatile("s_waitcnt lgkmcnt(0)" ::: "memory"); \
  __builtin_amdgcn_s_barrier(); \
  asm volatile("" ::: "memory"); } while (0)

// Pre-swizzle W1 (f32 [256][256], k-major) into MFMA B-fragment order, bf16.
// W1f[((cc*8+kk)*64 + lane)*8 + j] = bf16(W1[kk*32 + 8*(lane>>4) + j][cc*16 + (lane&15)])
__global__ void prep_w1_kernel(const float* __restrict__ W1, unsigned short* __restrict__ W1f) {
  const int bx = blockIdx.x;   // cc*8 + kk, 0..127
  const int l = threadIdx.x;   // 0..63
  const int cc = bx >> 3, kk = bx & 7;
  const int h = cc * 16 + (l & 15);
  const int kbase = kk * 32 + ((l >> 4) << 3);
  bfrag_t pk;
#pragma unroll
  for (int j = 0; j < 8; ++j) pk[j] = (short)f2bf(W1[(size_t)(kbase + j) * 256 + h]);
  *(bfrag_t*)(W1f + (size_t)(bx * 64 + l) * 8) = pk;
}

__attribute__((amdgpu_flat_work_group_size(512, 512), amdgpu_waves_per_eu(2, 2)))
__global__ void attnpool_kernel(const float* __restrict__ x,
                                const int* __restrict__ batch,
                                const unsigned short* __restrict__ W1f,
                                const float* __restrict__ b1,
                                const float* __restrict__ W2,
                                const float* __restrict__ b2,
                                float* __restrict__ out,   // raw weighted sums (zeroed)
                                float* __restrict__ Zp,    // softmax denominator (zeroed)
                                int N, int base, int rem) {
  extern __shared__ char smem[];
  char* Bl = smem;                           // B frags 0..126, frag-linear
  char* xt = smem + XT_OFF;                  // [64 rows][512B] bf16 tile, swizzled
  float* spart = (float*)(smem + SPART_OFF); // [2 cg][64 rows] score partials

  const int t = threadIdx.x;
  const int lane = t & 63;
  const int wv = t >> 6;        // 0..7
  const int rg = wv & 3;        // row group: rows rg*16..+15
  const int cg = wv >> 2;       // cc group: cc cg*8..+7
  const int l15 = lane & 15;
  const int hi = lane >> 4;

  const int blk = blockIdx.x;
  const int cnt = base + (blk < rem ? 1 : 0);
  const int tile0 = blk * base + min(blk, rem);

  // ---- B -> LDS (frag-linear, GLD16; zero registers). frag 127 stays in L2 ----
#pragma unroll
  for (int i = 0; i < 16; ++i) {
    const int f = wv * 16 + i;
    if (f < B_FRAGS) GLD16(W1f + (size_t)f * 512 + lane * 8, Bl + f * 1024);
  }

  // per-lane constants for my 8 cc's
  float b1v[8], w2v[8];
#pragma unroll
  for (int i = 0; i < 8; ++i) {
    b1v[i] = b1[(cg * 8 + i) * 16 + l15];
    w2v[i] = W2[(cg * 8 + i) * 16 + l15];
  }
  const float b2c = b2[0];

  // ---- cooperative 2-deep reg staging: 512 threads stage 64 rows ----
  const int srow = t >> 5;    // 0..15
  const int soct = t & 31;
  f32x4 sA[8], sB[8];
  auto issue_loads = [&](int tile, f32x4 (&sreg)[8]) {
#pragma unroll
    for (int p = 0; p < 4; ++p) {
      const int row = p * 16 + srow;
      const int rgb = min(tile * TROWS + row, N - 1);
      const float* s = x + (size_t)rgb * 256 + soct * 8;
      sreg[2 * p] = *(const f32x4*)s;
      sreg[2 * p + 1] = *(const f32x4*)(s + 4);
    }
  };
  auto write_tile = [&](f32x4 (&sreg)[8]) {
#pragma unroll
    for (int p = 0; p < 4; ++p) {
      const int row = p * 16 + srow;
      *(bfrag_t*)(xt + row * 512 + ((soct * 16) ^ ((row & 7) << 4))) =
          pack8(sreg[2 * p], sreg[2 * p + 1]);
    }
  };

  float zacc = 0.f;
  f32x4 pacc = {0.f, 0.f, 0.f, 0.f};
  int gcur = -1;

  auto flush = [&]() {
    float* po = out + (size_t)gcur * 256 + lane * 4;
    atomicAdd(po + 0, pacc[0]); atomicAdd(po + 1, pacc[1]);
    atomicAdd(po + 2, pacc[2]); atomicAdd(po + 3, pacc[3]);
    pacc[0] = pacc[1] = pacc[2] = pacc[3] = 0.f;
  };

  // body(t): LDS holds tile t; sWr holds tile t+1 (issued one body ago);
  // issues tile t+2 into sIss at the top (in flight across the whole body).
  auto body = [&](int tt, f32x4 (&sIss)[8], f32x4 (&sWr)[8]) {
    const int tile = tile0 + tt;
    const int R0 = tile * TROWS;

    if (tt + 2 < cnt) issue_loads(tile + 2, sIss);

    // ---- A-frags: rows rg*16..+15 from swizzled LDS ----
    bfrag_t A0[8];
    {
      const int arow = rg * 16 + l15;
      const int sw = (l15 & 7) << 4;
      const char* ap = xt + arow * 512;
#pragma unroll
      for (int kk = 0; kk < 8; ++kk)
        A0[kk] = *(const bfrag_t*)(ap + ((kk * 64 + hi * 16) ^ sw));
    }

    // ---- partial score over my 8 cc's ----
    float s0v[4] = {0.f, 0.f, 0.f, 0.f};
#pragma unroll
    for (int i = 0; i < 8; ++i) {
      const int cc = cg * 8 + i;
      f32x4 acc = {0.f, 0.f, 0.f, 0.f};
#pragma unroll
      for (int kk = 0; kk < 8; ++kk) {
        const int frag = cc * 8 + kk;
        bfrag_t Bk;
        if (frag == B_FRAGS)   // wave-uniform; only (cg=1,i=7,kk=7)
          Bk = *(const bfrag_t*)(W1f + (size_t)frag * 512 + lane * 8);
        else
          Bk = *(const bfrag_t*)(Bl + frag * 1024 + lane * 16);
        acc = __builtin_amdgcn_mfma_f32_16x16x32_bf16(A0[kk], Bk, acc, 0, 0, 0);
      }
#pragma unroll
      for (int r = 0; r < 4; ++r)
        s0v[r] += tanh_fast(acc[r] + b1v[i]) * w2v[i];
    }

    // reduce over l15
#pragma unroll
    for (int r = 0; r < 4; ++r) {
      float v = s0v[r];
      v += __shfl_xor(v, 1); v += __shfl_xor(v, 2);
      v += __shfl_xor(v, 4); v += __shfl_xor(v, 8);
      s0v[r] = v;
    }
    if (l15 == 0) {
#pragma unroll
      for (int r = 0; r < 4; ++r)
        spart[cg * 64 + rg * 16 + hi * 4 + r] = s0v[r];
    }
    BAR_LGKM();   // SYNC1: partials visible (global loads stay in flight)

    // ---- combine partner partial, exp ----
    f32x4 w0v;
#pragma unroll
    for (int r = 0; r < 4; ++r) {
      const int row = rg * 16 + hi * 4 + r;
      const float s = s0v[r] + spart[(cg ^ 1) * 64 + row] + b2c;
      w0v[r] = (R0 + row < N) ? __expf(s) : 0.f;
    }
    if (cg == 0) {
      float z = w0v[0] + w0v[1] + w0v[2] + w0v[3];
      z += __shfl_xor(z, 16);
      z += __shfl_xor(z, 32);
      zacc += z;
    }

    // wlane: lane L holds w[rg*16 + (L&15)]
    float wlane;
    {
      const int rq = lane & 3;
      const float ca = (rq == 0) ? w0v[0] : w0v[1];
      const float cb = (rq == 2) ? w0v[2] : w0v[3];
      const float c = (rq < 2) ? ca : cb;
      const int srcl = (((lane >> 2) & 3) << 4) + rq;
      wlane = __shfl(c, srcl);
    }

    int bid = batch[min(R0 + rg * 16 + l15, N - 1)];

    // ---- pool my half (8 rows: rg*16 + cg*8 ..); lane owns cols 4*lane..+3 ----
    const int g_first = __builtin_amdgcn_readlane(bid, cg * 8);
    const int g_last = __builtin_amdgcn_readlane(bid, cg * 8 + 7);
    if (g_first != gcur) { if (gcur >= 0) flush(); gcur = g_first; }
    const int rowb = rg * 16 + cg * 8;
    if (g_first == g_last) {
#pragma unroll
      for (int r = 0; r < 8; ++r) {
        const float wr = readlane_f(wlane, cg * 8 + r);
        const int row = rowb + r;
        const u32x2 v = *(const u32x2*)(xt + row * 512 + ((lane * 8) ^ ((row & 7) << 4)));
        pacc[0] = __builtin_fmaf(wr, __uint_as_float(v[0] << 16), pacc[0]);
        pacc[1] = __builtin_fmaf(wr, __uint_as_float(v[0] & 0xffff0000u), pacc[1]);
        pacc[2] = __builtin_fmaf(wr, __uint_as_float(v[1] << 16), pacc[2]);
        pacc[3] = __builtin_fmaf(wr, __uint_as_float(v[1] & 0xffff0000u), pacc[3]);
      }
    } else {
      for (int r = 0; r < 8; ++r) {
        const int g = __builtin_amdgcn_readlane(bid, cg * 8 + r);
        if (g != gcur) { flush(); gcur = g; }
        const float wr = readlane_f(wlane, cg * 8 + r);
        const int row = rowb + r;
        const u32x2 v = *(const u32x2*)(xt + row * 512 + ((lane * 8) ^ ((row & 7) << 4)));
        pacc[0] = __builtin_fmaf(wr, __uint_as_float(v[0] << 16), pacc[0]);
        pacc[1] = __builtin_fmaf(wr, __uint_as_float(v[0] & 0xffff0000u), pacc[1]);
        pacc[2] = __builtin_fmaf(wr, __uint_as_float(v[1] << 16), pacc[2]);
        pacc[3] = __builtin_fmaf(wr, __uint_as_float(v[1] & 0xffff0000u), pacc[3]);
      }
    }

    BAR_LGKM();   // SYNC2: all reads of tile t retired
    if (tt + 1 < cnt) write_tile(sWr);   // counted vmcnt via reg dep (t+2 stays in flight)
    BAR_LGKM();   // SYNC3: tile t+1 visible
  };

  // ---- prologue ----
  issue_loads(tile0, sA);
  write_tile(sA);                      // implicit vmcnt wait also drains B's GLD16s
  if (cnt > 1) issue_loads(tile0 + 1, sB);
  BAR_LGKM();                          // B + tile0 visible

  int tt = 0;
  for (;;) {
    body(tt, sA, sB);
    if (++tt >= cnt) break;
    body(tt, sB, sA);
    if (++tt >= cnt) break;
  }

  if (gcur >= 0) flush();
  if (lane == 0 && zacc != 0.f) atomicAdd(Zp, zacc);
}

__global__ void finalize_kernel(float* __restrict__ out, const float* __restrict__ Zp, int n4) {
  const int i = blockIdx.x * blockDim.x + threadIdx.x;
  if (i < n4) {
    const float zi = 1.f / Zp[0];
    f32x4* p = (f32x4*)out;
    f32x4 v = p[i];
    v[0] *= zi; v[1] *= zi; v[2] *= zi; v[3] *= zi;
    p[i] = v;
  }
}

extern "C" void kernel_launch(void* const* d_in, const int* in_sizes, int n_in,
                              void* d_out, int out_size, void* d_ws, size_t ws_size,
                              hipStream_t stream) {
  const float* x  = (const float*)d_in[0];
  const int* batch = (const int*)d_in[1];
  const float* W1 = (const float*)d_in[2];
  const float* b1 = (const float*)d_in[3];
  const float* W2 = (const float*)d_in[4];
  const float* b2 = (const float*)d_in[5];
  float* out = (float*)d_out;
  const int N = in_sizes[1];

  unsigned short* W1f = (unsigned short*)d_ws;          // 128 KB
  float* Zp = (float*)((char*)d_ws + 131072);           // 4 B

  static int attr_done = 0;  // host-side only; idempotent attribute, not kernel state
  if (!attr_done) {
    hipFuncSetAttribute((const void*)attnpool_kernel,
                        hipFuncAttributeMaxDynamicSharedMemorySize, SMEM_BYTES);
    attr_done = 1;
  }

  const int ntiles = (N + TROWS - 1) / TROWS;
  const int base = ntiles / NBLOCKS;
  const int rem = ntiles % NBLOCKS;

  hipMemsetAsync(d_out, 0, (size_t)out_size * sizeof(float), stream);
  hipMemsetAsync(Zp, 0, sizeof(float), stream);
  prep_w1_kernel<<<128, 64, 0, stream>>>(W1, W1f);
  attnpool_kernel<<<NBLOCKS, 512, SMEM_BYTES, stream>>>(x, batch, W1f, b1, W2, b2,
                                                        out, Zp, N, base, rem);
  finalize_kernel<<<(out_size / 4 + 255) / 256, 256, 0, stream>>>(out, Zp, out_size / 4);
}